// Round 1
// baseline (207.018 us; speedup 1.0000x reference)
//
#include <hip/hip_runtime.h>

// SemanticConditioner: out = canvas + (embeddings @ W^T + residuals)[region_ids]
// B=4, N=65536, D=256, E=1536, R=512  (all fp32)

#define B_DIM 4
#define N_DIM 65536
#define D_DIM 256
#define E_DIM 1536
#define R_DIM 512
#define RPB   4   // embedding rows per block in the cond GEMM

// ---------------------------------------------------------------------------
// Kernel 1: transpose W [D][E] -> Wt [E][D]  (1.5 MB, LDS-tiled, coalesced both sides)
// grid (E/32, D/32) = (48, 8), 256 threads
// ---------------------------------------------------------------------------
__global__ __launch_bounds__(256) void k_transpose(const float* __restrict__ W,
                                                   float* __restrict__ Wt) {
    __shared__ float t[32][33];  // +1 pad: conflict-free transpose
    const int eb = blockIdx.x * 32;
    const int db = blockIdx.y * 32;
    const int tx = threadIdx.x & 31;   // e within tile (read) / d within tile (write)
    const int ty = threadIdx.x >> 5;   // 0..7
#pragma unroll
    for (int j = 0; j < 4; ++j) {
        t[ty + 8 * j][tx] = W[(size_t)(db + ty + 8 * j) * E_DIM + eb + tx];
    }
    __syncthreads();
#pragma unroll
    for (int j = 0; j < 4; ++j) {
        Wt[(size_t)(eb + ty + 8 * j) * D_DIM + db + tx] = t[tx][ty + 8 * j];
    }
}

// ---------------------------------------------------------------------------
// Kernel 2: cond[r][d] = sum_e emb[r][e] * Wt[e][d] + res[r][d]
// One block = 4 r-rows (staged in LDS) x all 256 d (one per thread).
// Wt reads are coalesced L2 hits; inner loop has no barriers -> deep pipelining.
// grid R/4 = 128 blocks, 256 threads
// ---------------------------------------------------------------------------
__global__ __launch_bounds__(256) void k_cond(const float* __restrict__ emb,
                                              const float* __restrict__ Wt,
                                              const float* __restrict__ res,
                                              float* __restrict__ cond) {
    __shared__ float4 embs[RPB][E_DIM / 4];  // 24 KB
    const int r0 = blockIdx.x * RPB;
    const int d  = threadIdx.x;

    const float4* eg = reinterpret_cast<const float4*>(emb) + (size_t)r0 * (E_DIM / 4);
#pragma unroll
    for (int t = 0; t < (RPB * E_DIM / 4) / 256; ++t) {  // 6 float4 loads/thread, coalesced
        int f = t * 256 + d;
        embs[f / (E_DIM / 4)][f % (E_DIM / 4)] = eg[f];
    }
    __syncthreads();

    float acc0 = 0.f, acc1 = 0.f, acc2 = 0.f, acc3 = 0.f;
#pragma unroll 8
    for (int g = 0; g < E_DIM / 4; ++g) {
        const float4 a0 = embs[0][g];
        const float4 a1 = embs[1][g];
        const float4 a2 = embs[2][g];
        const float4 a3 = embs[3][g];
        const int e = 4 * g;
        const float w0 = Wt[(size_t)(e + 0) * D_DIM + d];
        const float w1 = Wt[(size_t)(e + 1) * D_DIM + d];
        const float w2 = Wt[(size_t)(e + 2) * D_DIM + d];
        const float w3 = Wt[(size_t)(e + 3) * D_DIM + d];
        acc0 += a0.x * w0 + a0.y * w1 + a0.z * w2 + a0.w * w3;
        acc1 += a1.x * w0 + a1.y * w1 + a1.z * w2 + a1.w * w3;
        acc2 += a2.x * w0 + a2.y * w1 + a2.z * w2 + a2.w * w3;
        acc3 += a3.x * w0 + a3.y * w1 + a3.z * w2 + a3.w * w3;
    }
    cond[(size_t)(r0 + 0) * D_DIM + d] = acc0 + res[(size_t)(r0 + 0) * D_DIM + d];
    cond[(size_t)(r0 + 1) * D_DIM + d] = acc1 + res[(size_t)(r0 + 1) * D_DIM + d];
    cond[(size_t)(r0 + 2) * D_DIM + d] = acc2 + res[(size_t)(r0 + 2) * D_DIM + d];
    cond[(size_t)(r0 + 3) * D_DIM + d] = acc3 + res[(size_t)(r0 + 3) * D_DIM + d];
}

// ---------------------------------------------------------------------------
// Kernel 3: out = canvas + cond[region_ids]   (the 512 MB memory-bound pass)
// float4 per lane; each wave covers one (b,n) row -> region_ids load is
// wave-uniform; cond gather is a coalesced 1 KB L2-resident row read.
// ---------------------------------------------------------------------------
__global__ __launch_bounds__(256) void k_add(const float4* __restrict__ canvas,
                                             const int* __restrict__ rid,
                                             const float4* __restrict__ cond,
                                             float4* __restrict__ out) {
    const int total  = B_DIM * N_DIM * (D_DIM / 4);  // 16,777,216 float4
    const int stride = gridDim.x * blockDim.x;
    for (int i = blockIdx.x * blockDim.x + threadIdx.x; i < total; i += stride) {
        const int d4 = i & 63;               // float4 index within D
        const int n  = (i >> 6) & (N_DIM - 1);
        const int r  = rid[n];               // wave-uniform
        const float4 c = canvas[i];
        const float4 a = cond[r * (D_DIM / 4) + d4];
        float4 o;
        o.x = c.x + a.x;
        o.y = c.y + a.y;
        o.z = c.z + a.z;
        o.w = c.w + a.w;
        out[i] = o;
    }
}

// ---------------------------------------------------------------------------
extern "C" void kernel_launch(void* const* d_in, const int* in_sizes, int n_in,
                              void* d_out, int out_size, void* d_ws, size_t ws_size,
                              hipStream_t stream) {
    const float* canvas = (const float*)d_in[0];  // [B,N,D]
    const float* emb    = (const float*)d_in[1];  // [R,E]
    const float* W      = (const float*)d_in[2];  // [D,E]
    const float* res    = (const float*)d_in[3];  // [R,D]
    const int*   rid    = (const int*)d_in[4];    // [N]
    float* out = (float*)d_out;

    // workspace layout: Wt (E*D fp32 = 1.5 MB) | cond (R*D fp32 = 0.5 MB)
    float* Wt   = (float*)d_ws;
    float* cond = (float*)d_ws + (size_t)E_DIM * D_DIM;

    dim3 tgrid(E_DIM / 32, D_DIM / 32);  // (48, 8)
    k_transpose<<<tgrid, 256, 0, stream>>>(W, Wt);
    k_cond<<<R_DIM / RPB, 256, 0, stream>>>(emb, Wt, res, cond);
    k_add<<<2048, 256, 0, stream>>>((const float4*)canvas, rid,
                                    (const float4*)cond, (float4*)out);
}

// Round 3
// 136.547 us; speedup vs baseline: 1.5161x; 1.5161x over previous
//
#include <hip/hip_runtime.h>

// SemanticConditioner: out = canvas + (embeddings @ W^T + residuals)[region_ids]
// B=4, N=65536, D=256, E=1536, R=512  (all fp32)

#define B_DIM 4
#define N_DIM 65536
#define D_DIM 256
#define E_DIM 1536
#define R_DIM 512
#define RPB   4     // embedding rows per block (cond GEMM)
#define KS    4     // K-splits (cond GEMM)
#define KSUB  (E_DIM / KS)      // 384
#define KSUB4 (KSUB / 4)        // 96

// native clang vector type: required by __builtin_nontemporal_{load,store}
typedef float f32x4 __attribute__((ext_vector_type(4)));

// ---------------------------------------------------------------------------
// Kernel 1: transpose W [D][E] -> Wt [E][D]
// grid (E/32, D/32) = (48, 8), 256 threads
// ---------------------------------------------------------------------------
__global__ __launch_bounds__(256) void k_transpose(const float* __restrict__ W,
                                                   float* __restrict__ Wt) {
    __shared__ float t[32][33];
    const int eb = blockIdx.x * 32;
    const int db = blockIdx.y * 32;
    const int tx = threadIdx.x & 31;
    const int ty = threadIdx.x >> 5;
#pragma unroll
    for (int j = 0; j < 4; ++j)
        t[ty + 8 * j][tx] = W[(size_t)(db + ty + 8 * j) * E_DIM + eb + tx];
    __syncthreads();
#pragma unroll
    for (int j = 0; j < 4; ++j)
        Wt[(size_t)(eb + ty + 8 * j) * D_DIM + db + tx] = t[tx][ty + 8 * j];
}

// ---------------------------------------------------------------------------
// Kernel 2: partial GEMM  part[ks][r][d] = sum_{e in ks-chunk} emb[r][e]*Wt[e][d]
// grid (R/RPB, KS) = (128, 4) = 512 blocks (2/CU), 256 threads
// ---------------------------------------------------------------------------
__global__ __launch_bounds__(256) void k_cond_part(const float* __restrict__ emb,
                                                   const float* __restrict__ Wt,
                                                   float* __restrict__ part) {
    __shared__ f32x4 embs[RPB][KSUB4];  // 6 KB
    const int r0 = blockIdx.x * RPB;
    const int ks = blockIdx.y;
    const int d  = threadIdx.x;

    // stage emb[r0..r0+3][ks*KSUB .. +KSUB) : RPB*KSUB4 = 384 float4
    const f32x4* eg = reinterpret_cast<const f32x4*>(emb);
    for (int f = d; f < RPB * KSUB4; f += 256) {
        const int rr = f / KSUB4, gg = f % KSUB4;
        embs[rr][gg] = eg[(size_t)(r0 + rr) * (E_DIM / 4) + ks * KSUB4 + gg];
    }
    __syncthreads();

    float acc0 = 0.f, acc1 = 0.f, acc2 = 0.f, acc3 = 0.f;
    const int ebase = ks * KSUB;
#pragma unroll 8
    for (int g = 0; g < KSUB4; ++g) {
        const f32x4 a0 = embs[0][g];
        const f32x4 a1 = embs[1][g];
        const f32x4 a2 = embs[2][g];
        const f32x4 a3 = embs[3][g];
        const int e = ebase + 4 * g;
        const float w0 = Wt[(size_t)(e + 0) * D_DIM + d];
        const float w1 = Wt[(size_t)(e + 1) * D_DIM + d];
        const float w2 = Wt[(size_t)(e + 2) * D_DIM + d];
        const float w3 = Wt[(size_t)(e + 3) * D_DIM + d];
        acc0 += a0.x * w0 + a0.y * w1 + a0.z * w2 + a0.w * w3;
        acc1 += a1.x * w0 + a1.y * w1 + a1.z * w2 + a1.w * w3;
        acc2 += a2.x * w0 + a2.y * w1 + a2.z * w2 + a2.w * w3;
        acc3 += a3.x * w0 + a3.y * w1 + a3.z * w2 + a3.w * w3;
    }
    float* p = part + ((size_t)ks * R_DIM + r0) * D_DIM + d;
    p[0 * D_DIM] = acc0;
    p[1 * D_DIM] = acc1;
    p[2 * D_DIM] = acc2;
    p[3 * D_DIM] = acc3;
}

// ---------------------------------------------------------------------------
// Kernel 3: cond[r][d] = sum_ks part[ks][r][d] + res[r][d]
// grid R*D/256 = 512 blocks, 256 threads
// ---------------------------------------------------------------------------
__global__ __launch_bounds__(256) void k_reduce(const float* __restrict__ part,
                                                const float* __restrict__ res,
                                                float* __restrict__ cond) {
    const int i = blockIdx.x * 256 + threadIdx.x;  // r*D + d
    const size_t stride = (size_t)R_DIM * D_DIM;
    cond[i] = part[i] + part[i + stride] + part[i + 2 * stride] +
              part[i + 3 * stride] + res[i];
}

// ---------------------------------------------------------------------------
// Kernel 4: out = canvas + cond[region_ids]   (512 MB memory-bound pass)
// Non-temporal canvas/out so the streams don't evict the L2-resident cond
// table. Unroll-2 grid-stride: two independent rid->cond->add chains in flight.
// ---------------------------------------------------------------------------
__global__ __launch_bounds__(256) void k_add(const f32x4* __restrict__ canvas,
                                             const int* __restrict__ rid,
                                             const f32x4* __restrict__ cond,
                                             f32x4* __restrict__ out) {
    const int stride = gridDim.x * blockDim.x;          // 524288
    int i = blockIdx.x * blockDim.x + threadIdx.x;
    // total = 16,777,216 = 32 * stride (exact), process 2 per loop
#pragma unroll 1
    for (int it = 0; it < 16; ++it, i += 2 * stride) {
        const int j  = i + stride;
        const int n0 = (i >> 6) & (N_DIM - 1);
        const int n1 = (j >> 6) & (N_DIM - 1);
        const int r0 = rid[n0];
        const int r1 = rid[n1];
        const f32x4 c0 = __builtin_nontemporal_load(&canvas[i]);
        const f32x4 c1 = __builtin_nontemporal_load(&canvas[j]);
        const f32x4 a0 = cond[r0 * (D_DIM / 4) + (i & 63)];
        const f32x4 a1 = cond[r1 * (D_DIM / 4) + (j & 63)];
        __builtin_nontemporal_store(c0 + a0, &out[i]);
        __builtin_nontemporal_store(c1 + a1, &out[j]);
    }
}

// ---------------------------------------------------------------------------
extern "C" void kernel_launch(void* const* d_in, const int* in_sizes, int n_in,
                              void* d_out, int out_size, void* d_ws, size_t ws_size,
                              hipStream_t stream) {
    const float* canvas = (const float*)d_in[0];  // [B,N,D]
    const float* emb    = (const float*)d_in[1];  // [R,E]
    const float* W      = (const float*)d_in[2];  // [D,E]
    const float* res    = (const float*)d_in[3];  // [R,D]
    const int*   rid    = (const int*)d_in[4];    // [N]

    // ws layout: Wt (E*D) | part (KS*R*D) | cond (R*D)   -- all fp32
    float* Wt   = (float*)d_ws;
    float* part = Wt + (size_t)E_DIM * D_DIM;
    float* cond = part + (size_t)KS * R_DIM * D_DIM;

    dim3 tgrid(E_DIM / 32, D_DIM / 32);
    k_transpose<<<tgrid, 256, 0, stream>>>(W, Wt);
    dim3 cgrid(R_DIM / RPB, KS);
    k_cond_part<<<cgrid, 256, 0, stream>>>(emb, Wt, part);
    k_reduce<<<(R_DIM * D_DIM) / 256, 256, 0, stream>>>(part, res, cond);
    k_add<<<2048, 256, 0, stream>>>((const f32x4*)canvas, rid,
                                    (const f32x4*)cond, (f32x4*)d_out);
}